// Round 11
// baseline (138.722 us; speedup 1.0000x reference)
//
#include <hip/hip_runtime.h>

// Signature-kernel MMD via Goursat PDE — round 12.
// Round-11 postmortem (decisive null): pins + cap-72 changed NOTHING vs r8
// (92.3 vs 92.1us, no spill) -> dY residency irrelevant; gather-stall
// theory dead. Refit at the m07-implied sustained clock (~1.7GHz):
// r8's ~50 instr/row ~= 105cy ~= measured busy time -> the kernel is
// ISSUE-BOUND; the "28% idle" is a clock-domain artifact. Only lever left:
// fewer instructions/row. 32 of 50 are the fp32 dot FMAs (hard floor 41us
// at the 103TF fma rate in fp32).
// Round-12: v_dot2_f32_f16 (__builtin_amdgcn_fdot2) — 2-way f16 dot with
// f32 accumulate. sig_diff packs increments as half2; PDE row = 16 dot2
// instead of 32 fma (~34 instr/row, 0.68x). Precision: f16 quantization
// -> inc err ~1e-5 (declared risk; absmax leaves 0.0 for the first time).
// Structure otherwise = proven r8/r11: LDS dX staging (now 4KB), 2112
// blocks, block-uniform decode, fused atomic reduce, no pins.

#define XY_BLOCKS 1024
#define TRI_BLOCKS 544
#define NBT (XY_BLOCKS + 2 * TRI_BLOCKS)        // 2112 blocks
#define DINCH_PER 65024                         // dwords per matrix (64*127*8)

typedef _Float16 h2 __attribute__((ext_vector_type(2)));

__device__ __forceinline__ float fdot2u(unsigned a, unsigned b, float c) {
#if __has_builtin(__builtin_amdgcn_fdot2)
    return __builtin_amdgcn_fdot2(__builtin_bit_cast(h2, a),
                                  __builtin_bit_cast(h2, b), c, false);
#else
    h2 ha = __builtin_bit_cast(h2, a), hb = __builtin_bit_cast(h2, b);
    return c + (float)ha.x * (float)hb.x + (float)ha.y * (float)hb.y;
#endif
}

__device__ __forceinline__ unsigned packh2(float a, float b) {
    _Float16 ha = (_Float16)a, hb = (_Float16)b;
    return (unsigned)__builtin_bit_cast(unsigned short, ha) |
           ((unsigned)__builtin_bit_cast(unsigned short, hb) << 16);
}

template <int C, int RM, int BM, bool BC>
__device__ __forceinline__ float dpp0(float x) {
    return __builtin_bit_cast(float, __builtin_amdgcn_update_dpp(
        0, __builtin_bit_cast(int, x), C, RM, BM, BC));
}

// 64-lane inclusive prefix sum, pure VALU (6 dependent adds).
__device__ __forceinline__ float wave_scan_incl(float v) {
    v += dpp0<0x111, 0xf, 0xf, true>(v);   // row_shr:1
    v += dpp0<0x112, 0xf, 0xf, true>(v);   // row_shr:2
    v += dpp0<0x114, 0xf, 0xf, true>(v);   // row_shr:4
    v += dpp0<0x118, 0xf, 0xf, true>(v);   // row_shr:8
    v += dpp0<0x142, 0xa, 0xf, false>(v);  // row_bcast:15 -> rows 1,3
    v += dpp0<0x143, 0xc, 0xf, false>(v);  // row_bcast:31 -> rows 2,3
    return v;
}

// lane l gets lane l-1's x; lane 0 gets `oldv`.
__device__ __forceinline__ float wave_shr1(float x, float oldv) {
    return __builtin_bit_cast(float, __builtin_amdgcn_update_dpp(
        __builtin_bit_cast(int, oldv), __builtin_bit_cast(int, x),
        0x138, 0xf, 0xf, false));          // wave_shr:1
}

// ---- kernel 1: path increments X,Y -> ws as PACKED HALF2 ----
// dword layout: which*65024 + a*1016 + r*8 + k  (k-th dword = dims 2k,2k+1)
// Also zeroes out[0] for the fused atomic reduction in sig_pde12.
__global__ __launch_bounds__(256) void sig_diff_h(
    const float* __restrict__ X, const float* __restrict__ Y,
    unsigned* __restrict__ dIncH, float* __restrict__ out)
{
    if (blockIdx.x == 0 && threadIdx.x == 0) out[0] = 0.0f;
    int i = blockIdx.x * 256 + threadIdx.x;   // float4 id, 65024 total
    if (i >= 65024) return;
    int which = (i >= 32512) ? 1 : 0;
    int j = i - which * 32512;
    int a = j / 508;                          // 127*4 float4 per path
    int rq = j - a * 508;                     // r*4 + q
    const float* S = which ? Y : X;
    const float4* p = (const float4*)(S + a * 2048) + rq;
    float4 v0 = p[0], v1 = p[4];              // +16 floats = next row
    uint2 w;
    w.x = packh2(v1.x - v0.x, v1.y - v0.y);
    w.y = packh2(v1.z - v0.z, v1.w - v0.w);
    ((uint2*)dIncH)[(which * DINCH_PER + a * 1016 + rq * 2) >> 1] = w;
}

// ---- kernel 2: PDE. 2112 blocks * 4 waves, one (g,a,b0) per block. ----
__global__ __launch_bounds__(256, 8) void sig_pde12(
    const unsigned* __restrict__ dIncH, float* __restrict__ out)
{
    __shared__ uint4 Xs[254];              // dX path, half2-packed (4064 B)
    __shared__ float red[4];
    const int wid  = threadIdx.x >> 6;
    const int lane = threadIdx.x & 63;
    const int BT   = blockIdx.x;

    // block-uniform decode -> (gram g, a, b0); b = b0 + wave id
    int g, a, b0;
    if (BT < XY_BLOCKS) {                  // XY: dense 64x64
        g = 2; a = BT >> 4; b0 = (BT & 15) << 2;
    } else {                               // XX / YY upper triangles
        int t = BT - XY_BLOCKS; g = 0;
        if (t >= TRI_BLOCKS) { t -= TRI_BLOCKS; g = 1; }
        int aa = 0;
        for (;;) { int nb = (67 - aa) >> 2; if (t < nb) break; t -= nb; ++aa; }
        a = aa; b0 = aa + (t << 2);
    }
    const int b = b0 + wid;

    const unsigned* dA = dIncH + ((g == 1) ? DINCH_PER : 0);   // row paths
    const unsigned* dB = dIncH + ((g == 0) ? 0 : DINCH_PER);   // col paths

    // stage the block-uniform dX path into LDS (1016 dwords = 254 uint4)
    {
        const uint4* Ap = (const uint4*)(dA + a * 1016);
        const int tid = threadIdx.x;
        if (tid < 254) Xs[tid] = Ap[tid];
    }
    __syncthreads();

    float acc = 0.0f;
    if (g == 2 || b <= 63) {               // dead triangle waves skip compute
        const float weight = (g == 2) ? (-2.0f / 4096.0f)
                                      : ((a == b ? 1.0f : 2.0f) / 4096.0f);

        // per-lane dY rows j=2l, 2l+1 (lane 63's 2nd row masked via c1)
        uint4 ya0, ya1, yb0, yb1;
        {
            const unsigned* Qb = dB + b * 1016;
            const int j0 = lane << 1;
            const int j1 = (j0 + 1 < 127) ? j0 + 1 : 126;
            const uint4* A4 = (const uint4*)(Qb + j0 * 8);
            const uint4* B4 = (const uint4*)(Qb + j1 * 8);
            ya0 = A4[0]; ya1 = A4[1];
            yb0 = B4[0]; yb1 = B4[1];
        }

        float g_lo = 1.0f, g_hi = 1.0f;    // G[r][2l+1], G[r][2l+2]
        const bool last = (lane == 63);

#pragma unroll 1
        for (int r = 0; r < 127; ++r) {
            // broadcast row read: 2x ds_read_b128, uniform address
            const uint4 x0 = Xs[2*r], x1 = Xs[2*r + 1];

            // inc - 1 via two f16-dot2 chains per dot, seeds -0.5 each
            float s0 = -0.5f, s1 = -0.5f, t0 = -0.5f, t1 = -0.5f;
            s0 = fdot2u(x0.x, ya0.x, s0);  s1 = fdot2u(x0.y, ya0.y, s1);
            t0 = fdot2u(x0.x, yb0.x, t0);  t1 = fdot2u(x0.y, yb0.y, t1);
            s0 = fdot2u(x0.z, ya0.z, s0);  s1 = fdot2u(x0.w, ya0.w, s1);
            t0 = fdot2u(x0.z, yb0.z, t0);  t1 = fdot2u(x0.w, yb0.w, t1);
            s0 = fdot2u(x1.x, ya1.x, s0);  s1 = fdot2u(x1.y, ya1.y, s1);
            t0 = fdot2u(x1.x, yb1.x, t0);  t1 = fdot2u(x1.y, yb1.y, t1);
            s0 = fdot2u(x1.z, ya1.z, s0);  s1 = fdot2u(x1.w, ya1.w, s1);
            t0 = fdot2u(x1.z, yb1.z, t0);  t1 = fdot2u(x1.w, yb1.w, t1);
            const float i0 = s0 + s1;          // inc(r, 2l)   - 1
            const float i1 = t0 + t1;          // inc(r, 2l+1) - 1

            const float gl = wave_shr1(g_hi, 1.0f);     // G[r][2l], lane0->1
            const float c0 = fmaf(gl, i0, g_lo);
            const float c1 = last ? 0.0f : fmaf(g_lo, i1, g_hi);
            const float S = wave_scan_incl(c0 + c1);
            const float T = S + 1.0f;
            g_lo = T - c1;
            g_hi = T;
        }

        const float kab = __builtin_bit_cast(float,
            __builtin_amdgcn_readlane(__builtin_bit_cast(int, g_lo), 63));
        acc = weight * kab;
    }

    // fused reduction: 4 waves -> LDS -> one atomic per block
    if (lane == 0) red[wid] = acc;
    __syncthreads();
    if (threadIdx.x == 0)
        atomicAdd(out, (red[0] + red[1]) + (red[2] + red[3]));
}

__global__ __launch_bounds__(256) void sig_reduce2(
    const float* __restrict__ v, float* __restrict__ out, int n)
{
    __shared__ float red[256];
    float s = 0.0f;
    for (int i = threadIdx.x; i < n; i += 256) s += v[i];
    red[threadIdx.x] = s;
    __syncthreads();
    for (int st = 128; st > 0; st >>= 1) {
        if (threadIdx.x < st) red[threadIdx.x] += red[threadIdx.x + st];
        __syncthreads();
    }
    if (threadIdx.x == 0) out[0] = red[0];
}

// ---- fallback (ws too small for increment staging): round-1 kernel ----
__global__ __launch_bounds__(64) void sig_pde_kernel(
    const float* __restrict__ X, const float* __restrict__ Y,
    float* __restrict__ ws)
{
    __shared__ float Xs[2048];
    const int T = blockIdx.x;
    const int g = T >> 12;
    const int t = T & 4095;
    const int a = t >> 6, b = t & 63;
    const int lane = threadIdx.x;
    if (g < 2 && a > b) { if (lane == 0) ws[T] = 0.0f; return; }
    const float* P = (g == 1) ? Y : X;
    const float* Q = (g == 0) ? X : Y;
    const float weight = (g == 2) ? (-2.0f / 4096.0f)
                                  : ((a == b ? 1.0f : 2.0f) / 4096.0f);
    {
        const float4* Pa = (const float4*)(P + a * 2048);
        float4* Xs4 = (float4*)Xs;
#pragma unroll
        for (int k = 0; k < 8; ++k) Xs4[lane + (k << 6)] = Pa[lane + (k << 6)];
    }
    __syncthreads();
    {
        float tmp[32];
#pragma unroll
        for (int k = 0; k < 32; ++k) {
            int idx = lane + (k << 6);
            tmp[k] = (idx < 2032) ? (Xs[idx + 16] - Xs[idx]) : 0.0f;
        }
        __syncthreads();
#pragma unroll
        for (int k = 0; k < 32; ++k) {
            int idx = lane + (k << 6);
            if (idx < 2032) Xs[idx] = tmp[k];
        }
    }
    __syncthreads();
    float y0[16], y1[16];
    {
        const float* Qb = Q + b * 2048;
        const int r0 = lane << 1;
        const int r2 = (r0 + 2 > 127) ? 127 : (r0 + 2);
        const float4* A4 = (const float4*)(Qb + r0 * 16);
        const float4* B4 = (const float4*)(Qb + (r0 + 1) * 16);
        const float4* C4 = (const float4*)(Qb + r2 * 16);
#pragma unroll
        for (int q = 0; q < 4; ++q) {
            float4 ra = A4[q], rb = B4[q], rc = C4[q];
            y0[4*q+0] = rb.x - ra.x;  y1[4*q+0] = rc.x - rb.x;
            y0[4*q+1] = rb.y - ra.y;  y1[4*q+1] = rc.y - rb.y;
            y0[4*q+2] = rb.z - ra.z;  y1[4*q+2] = rc.z - rb.z;
            y0[4*q+3] = rb.w - ra.w;  y1[4*q+3] = rc.w - rb.w;
        }
    }
    float g_lo = 1.0f, g_hi = 1.0f;
    const bool last = (lane == 63);
    for (int r = 0; r < 127; ++r) {
        const float* xrow = Xs + r * 16;
        float s0 = -0.5f, s1 = -0.5f, t0 = -0.5f, t1 = -0.5f;
#pragma unroll
        for (int d = 0; d < 16; d += 2) {
            s0 = fmaf(xrow[d], y0[d], s0);   s1 = fmaf(xrow[d+1], y0[d+1], s1);
            t0 = fmaf(xrow[d], y1[d], t0);   t1 = fmaf(xrow[d+1], y1[d+1], t1);
        }
        const float i0 = s0 + s1, i1 = t0 + t1;
        const float gl = wave_shr1(g_hi, 1.0f);
        const float c0 = fmaf(gl, i0, g_lo);
        const float c1 = last ? 0.0f : fmaf(g_lo, i1, g_hi);
        const float S = wave_scan_incl(c0 + c1);
        g_lo = (S - c1) + 1.0f;
        g_hi = S + 1.0f;
    }
    const float kab = __builtin_bit_cast(float,
        __builtin_amdgcn_readlane(__builtin_bit_cast(int, g_lo), 63));
    if (lane == 0) ws[T] = weight * kab;
}

extern "C" void kernel_launch(void* const* d_in, const int* in_sizes, int n_in,
                              void* d_out, int out_size, void* d_ws, size_t ws_size,
                              hipStream_t stream) {
    const float* X = (const float*)d_in[0];
    const float* Y = (const float*)d_in[1];
    float* out = (float*)d_out;

    const size_t need = (size_t)(2 * DINCH_PER) * sizeof(unsigned); // 508 KiB
    if (ws_size >= need) {
        unsigned* wsh = (unsigned*)d_ws;
        sig_diff_h<<<254, 256, 0, stream>>>(X, Y, wsh, out);
        sig_pde12<<<NBT, 256, 0, stream>>>(wsh, out);
    } else {
        float* ws = (float*)d_ws;
        sig_pde_kernel<<<12288, 64, 0, stream>>>(X, Y, ws);
        sig_reduce2<<<1, 256, 0, stream>>>(ws, out, 12288);
    }
}